// Round 1
// 598.753 us; speedup vs baseline: 1.0548x; 1.0548x over previous
//
#include <hip/hip_runtime.h>
#include <hip/hip_fp16.h>

// Problem constants
#define BSZ 32
#define CS_ 640
#define CT_ 768
#define NTOK 576
#define HID 64
#define ITERS 50
#define WGB 16           // workgroups per batch
#define ROWS 36          // rows of M per workgroup (576/16)
#define NWG (BSZ*WGB)    // 512 wgs = exactly 2 per CU (uniform), 32 waves/CU
#define MPITCH 640       // halves per Ms/E row (576 real + 64 pad)
#define XPITCH 68        // halves per staged x row

#define LOG2_N 9.169925001442312f         // log2(576)
#define INV_N 0.001736111111111111f       // 1/576
#define MS_SCALE 14.426950408889634f      // 10 * log2(e):  Ms' = M/reg * log2(e)
#define M_FROM_MSP 0.06931471805599453f   // ln2 / 10

// Workspace layout (bytes)
#define OFF_CNT 0              // 32 barrier counters, 64B apart (2048 B)
#define OFF_DONE 2048          // int
#define OFF_GSUM 2056          // float
#define OFF_DUMMY 2112         // 512 f32 (keep-alive sink)
#define OFF_SQS 4160           // sumsq [2][32][64] f32 (16384 B)
#define OFF_PACC 20544         // col-sum accumulators [2][32][576] f32 = 147456 B
#define MEMSET_BYTES 168000
#define OFF_XS 168000          // xs fp16 [32][576][64] = 2,359,296
#define OFF_XT 2527296         // xt fp16 [32][576][64] = 2,359,296 (end 4,886,592)

// k4 LDS layout (bytes); total 61,344 -> 2 wgs/CU (122,688 <= 163,840)
#define L_MS 0                 // 36*640*2 = 46080  (holds Ms during build, E = 2^(Ms-mrow) during iters)
#define L_U 46080              // 36*4 = 144  (log2-domain u', needed for final)
#define L_V 46224              // 640*4 = 2560 (ew_v = 2^v during iters; log2-domain v in final)
#define L_RED 48784            // 16*4 = 64
#define L_EU 48848             // 36*4 = 144  (eu = 2^u')
#define L_MROW 48992           // 36*4 = 144  (per-row max of Ms, for final M recovery)
#define L_UNION 49136          // iters: vtmp 576*2*4 = 4608
                               // build: ssc(256)+stc(256)+sqs(144)+sqt(2304)+xs_l(4896)+xt_l(4352) = 12208
#define SMEM_BYTES 61344

// ---------------------------------------------------------------------------
// K1 (unchanged): LDS-staged projection GEMM.
// ---------------------------------------------------------------------------
template <int C>
__device__ __forceinline__ void proj_body(
    const float* __restrict__ feat,   // [C][576] this batch
    const float* __restrict__ W,      // [64][C]
    const float* __restrict__ bias,   // [64]
    __half* __restrict__ out,         // [576][64] this batch
    float* __restrict__ sq,           // [64] this (side,batch)
    float (*fbuf)[64], int nblk)
{
    const int tid = threadIdx.x;
    const int lane = tid & 63;
    const int wv = __builtin_amdgcn_readfirstlane((int)(tid >> 6));
    const int h0 = wv * 8;
    const int n0 = nblk * 64;

    float acc[8];
#pragma unroll
    for (int i = 0; i < 8; i++) acc[i] = 0.f;

    const float* wbase = W + (size_t)h0 * C;
    for (int k = 0; k < (C >> 6); k++) {
        const int c0 = k << 6;
        __syncthreads();   // fbuf reuse
#pragma unroll
        for (int j = 0; j < 8; j++) {
            int idx = tid + j * 512;
            int cl = idx >> 6, tok = idx & 63;
            fbuf[cl][tok] = feat[(size_t)(c0 + cl) * NTOK + n0 + tok];
        }
        __syncthreads();
#pragma unroll 2
        for (int cc8 = 0; cc8 < 64; cc8 += 8) {
            float f[8];
#pragma unroll
            for (int j = 0; j < 8; j++) f[j] = fbuf[cc8 + j][lane];
#pragma unroll
            for (int hh = 0; hh < 8; hh++) {
                const float* wr = wbase + (size_t)hh * C + c0 + cc8;
#pragma unroll
                for (int j = 0; j < 8; j++) acc[hh] = fmaf(f[j], wr[j], acc[hh]);
            }
        }
    }
#pragma unroll
    for (int hh = 0; hh < 8; hh++) acc[hh] += bias[h0 + hh];

    __half2 hp[4];
#pragma unroll
    for (int hh = 0; hh < 8; hh += 2) hp[hh >> 1] = __floats2half2_rn(acc[hh], acc[hh + 1]);
    *(float4*)(out + (size_t)(n0 + lane) * HID + h0) = *(const float4*)hp;

#pragma unroll
    for (int hh = 0; hh < 8; hh++) {
        float v2 = acc[hh] * acc[hh];
#pragma unroll
        for (int off = 32; off > 0; off >>= 1) v2 += __shfl_xor(v2, off, 64);
        if (lane == 0) atomicAdd(sq + h0 + hh, v2);
    }
}

__global__ __launch_bounds__(512, 4) void k1_proj(
    const float* __restrict__ feat_s, const float* __restrict__ feat_t,
    const float* __restrict__ Ws, const float* __restrict__ bs,
    const float* __restrict__ Wt, const float* __restrict__ bt,
    __half* __restrict__ xs, __half* __restrict__ xt, float* __restrict__ sumsq)
{
    __shared__ float fbuf[64][64];
    const int nblk = blockIdx.x, b = blockIdx.y, st = blockIdx.z;
    if (st == 0) {
        proj_body<CS_>(feat_s + (size_t)b * CS_ * NTOK, Ws, bs,
                       xs + (size_t)b * NTOK * HID, sumsq + b * 64, fbuf, nblk);
    } else {
        proj_body<CT_>(feat_t + (size_t)b * CT_ * NTOK, Wt, bt,
                       xt + (size_t)b * NTOK * HID, sumsq + (BSZ + b) * 64, fbuf, nblk);
    }
}

// ---------------------------------------------------------------------------
// K4: persistent Sinkhorn, fence-free cross-WG protocol (unchanged), but with
// precomputed E = 2^(Ms - rowmax) so the 50-iteration hot loops are pure
// cvt+fma (no per-element exp2/log2). Row sums use ew_v = 2^v, col sums use
// eu = 2^u', both obtained by rcp (2^u' = (1/N)/rowsum). The Pacc column-sum
// values are algebraically identical to the previous version.
// ---------------------------------------------------------------------------
__global__ __launch_bounds__(1024, 8) void k4_sinkhorn(
    const __half* __restrict__ xsh, const __half* __restrict__ xth,
    const float* __restrict__ sumsq, float* __restrict__ Pacc,
    int* __restrict__ counters, int* __restrict__ done,
    float* __restrict__ gsum, float* __restrict__ dummyout,
    float* __restrict__ out)
{
    extern __shared__ char smem[];
    __half* Ms  = (__half*)(smem + L_MS);          // Ms during build, E during iters
    float* u_l  = (float*)(smem + L_U);
    float* ewv  = (float*)(smem + L_V);            // ew_v during iters; log-v in final
    float* red  = (float*)(smem + L_RED);
    float* eu_l = (float*)(smem + L_EU);
    float* mrow = (float*)(smem + L_MROW);
    float* vtmp = (float*)(smem + L_UNION);
    float* ssc  = (float*)(smem + L_UNION);
    float* stc  = (float*)(smem + L_UNION + 256);
    float* sqs  = (float*)(smem + L_UNION + 512);
    float* sqt  = (float*)(smem + L_UNION + 656);
    __half* xs_l = (__half*)(smem + L_UNION + 2960);
    __half* xt_l = (__half*)(smem + L_UNION + 7856);

    const int tid = threadIdx.x;
    const int b = blockIdx.x & 31, part = blockIdx.x >> 5;
    const int r0 = part * ROWS;
    const int lane = tid & 63, wv = tid >> 6;
    float dummy = 0.f;
    float s_kept = 0.f;

    if (tid < 64) {
        ssc[tid] = 1.0f / fmaxf(sqrtf(sumsq[b * 64 + tid]), 1e-12f);
    } else if (tid < 128) {
        stc[tid - 64] = 1.0f / fmaxf(sqrtf(sumsq[BSZ * 64 + b * 64 + (tid - 64)]), 1e-12f);
    }
    // ew_v = 2^v; v starts at 0 -> 1.0 (pad columns: 0 so they contribute nothing)
    for (int m = tid; m < MPITCH; m += 1024) ewv[m] = (m < NTOK) ? 1.0f : 0.f;
    __syncthreads();

    for (int idx = tid; idx < ROWS * 64; idx += 1024) {
        int r = idx >> 6, h = idx & 63;
        xs_l[r * XPITCH + h] =
            __float2half(__half2float(xsh[((size_t)b * NTOK + r0 + r) * 64 + h]) * ssc[h]);
    }
    if (tid < NTOK) {
        const __half* tp = xth + ((size_t)b * NTOK + tid) * 64;
        float s = 0.f;
#pragma unroll
        for (int h = 0; h < 64; h++) { float v = __half2float(tp[h]) * stc[h]; s = fmaf(v, v, s); }
        sqt[tid] = s;
    }
    __syncthreads();
    if (tid < ROWS) {
        float s = 0.f;
#pragma unroll
        for (int h = 0; h < 64; h++) { float v = __half2float(xs_l[tid * XPITCH + h]); s = fmaf(v, v, s); }
        sqs[tid] = s;
    }

    for (int c0 = 0; c0 < NTOK; c0 += 32) {
        __syncthreads();
        for (int idx = tid; idx < 32 * 64; idx += 1024) {
            int m = idx >> 6, h = idx & 63;
            xt_l[m * XPITCH + h] =
                __float2half(__half2float(xth[((size_t)b * NTOK + c0 + m) * 64 + h]) * stc[h]);
        }
        __syncthreads();
        for (int idx = tid; idx < ROWS * 32; idx += 1024) {
            int r = idx >> 5, c = idx & 31;
            const __half2* xr = (const __half2*)(xs_l + r * XPITCH);
            const __half2* tr = (const __half2*)(xt_l + c * XPITCH);
            float d = 0.f;
#pragma unroll
            for (int h2 = 0; h2 < 32; h2++) {
                float2 av = __half22float2(xr[h2]);
                float2 tv = __half22float2(tr[h2]);
                d = fmaf(av.x, tv.x, d);
                d = fmaf(av.y, tv.y, d);
            }
            float M = fmaxf(sqs[r] + sqt[c] - 2.f * d, 0.f);
            Ms[r * MPITCH + c0 + c] = __float2half(M * MS_SCALE);
        }
    }
    __syncthreads();
    for (int idx = tid; idx < ROWS * (MPITCH - NTOK); idx += 1024) {
        int r = idx >> 6, k = idx & 63;
        Ms[r * MPITCH + NTOK + k] = __float2half(-1000.f);
    }
    __syncthreads();

    // ---- One-time transform: Ms -> E = 2^(Ms - rowmax), record rowmax.
    // Per-row max self-cancels through the u/v algebra (u' = u + rowmax),
    // so Pacc column sums are identical to the untransformed computation.
    // Pad entries become exp2(-1000 - mx) = 0.
    for (int r = wv; r < ROWS; r += 16) {
        __half* row = Ms + r * MPITCH;
        float2 f[5];
        float mx = 0.f;   // real Ms >= 0, pad = -1000 never wins
#pragma unroll
        for (int j = 0; j < 5; j++) {
            f[j] = __half22float2(*(const __half2*)&row[128 * j + 2 * lane]);
            mx = fmaxf(mx, fmaxf(f[j].x, f[j].y));
        }
#pragma unroll
        for (int off = 32; off > 0; off >>= 1) mx = fmaxf(mx, __shfl_xor(mx, off, 64));
        if (lane == 0) mrow[r] = mx;
#pragma unroll
        for (int j = 0; j < 5; j++) {
            *(__half2*)&row[128 * j + 2 * lane] = __floats2half2_rn(
                __builtin_amdgcn_exp2f(f[j].x - mx), __builtin_amdgcn_exp2f(f[j].y - mx));
        }
    }
    __syncthreads();

    int* cnt = counters + b * 16;

    for (int it = 1; it <= ITERS; ++it) {
        if (it > 1) {
            if (tid < NTOK) {
                const int qr = (it - 1) & 1, qw = it & 1;
                float s = __hip_atomic_load(&Pacc[(size_t)(qr * BSZ + b) * NTOK + tid],
                                            __ATOMIC_RELAXED, __HIP_MEMORY_SCOPE_AGENT);
                ewv[tid] = INV_N * __builtin_amdgcn_rcpf(s);   // 2^v = (1/N)/colsum
                if (tid >= r0 && tid < r0 + ROWS) {
                    if (s_kept != 0.f)
                        dummy += __hip_atomic_fetch_add(
                            &Pacc[(size_t)(qw * BSZ + b) * NTOK + tid], -s_kept,
                            __ATOMIC_RELAXED, __HIP_MEMORY_SCOPE_AGENT);
                    s_kept = s;
                }
            }
            __syncthreads();
        }
        // ---- Row pass: rowsum_r = sum_c E_rc * ew_v_c  (pure cvt+fma)
        float2 vr[5];
#pragma unroll
        for (int j = 0; j < 5; j++) vr[j] = *(const float2*)&ewv[128 * j + 2 * lane];
        for (int r = wv; r < ROWS; r += 16) {
            const __half* row = Ms + r * MPITCH;
            float a = 0.f;
#pragma unroll
            for (int j = 0; j < 5; j++) {
                float2 f = __half22float2(*(const __half2*)&row[128 * j + 2 * lane]);
                a = fmaf(f.x, vr[j].x, a);
                a = fmaf(f.y, vr[j].y, a);
            }
#pragma unroll
            for (int off = 32; off > 0; off >>= 1) a += __shfl_xor(a, off, 64);
            if (lane == 0) {
                eu_l[r] = INV_N * __builtin_amdgcn_rcpf(a);    // 2^u' = (1/N)/rowsum
                u_l[r] = -LOG2_N - __builtin_amdgcn_logf(a);   // log2-domain u' for final
            }
        }
        __syncthreads();
        // ---- Col pass: partial colsum_c = sum_r E_rc * eu_r  (pure cvt+fma)
        if (tid < NTOK) {
            int hf = tid / 288, p = tid - hf * 288;
            const __half* col = Ms + 2 * p;
            float a0 = 0.f, a1 = 0.f;
            int n1 = hf * 18;
#pragma unroll
            for (int nn = 0; nn < 18; nn++, n1++) {
                float uu = eu_l[n1];
                float2 f = __half22float2(*(const __half2*)&col[n1 * MPITCH]);
                a0 = fmaf(f.x, uu, a0);
                a1 = fmaf(f.y, uu, a1);
            }
            ((float2*)vtmp)[hf * 288 + p] = make_float2(a0, a1);
        }
        __syncthreads();
        if (tid < NTOK) {
            float s = vtmp[tid] + vtmp[NTOK + tid];
            dummy += __hip_atomic_fetch_add(&Pacc[(size_t)((it & 1) * BSZ + b) * NTOK + tid], s,
                                            __ATOMIC_RELAXED, __HIP_MEMORY_SCOPE_AGENT);
        }
        __syncthreads();
        if (tid == 0) {
            __hip_atomic_fetch_add(cnt, 1, __ATOMIC_RELAXED, __HIP_MEMORY_SCOPE_AGENT);
            const int target = WGB * it;
            while (__hip_atomic_load(cnt, __ATOMIC_RELAXED, __HIP_MEMORY_SCOPE_AGENT) < target)
                __builtin_amdgcn_s_sleep(1);
        }
        __syncthreads();
    }

    // ---- Final: v (log2 domain) from Pacc; T*M with M = (log2(E) + rowmax) * ln2/10
    float* v_log = ewv;   // reuse buffer
    if (tid < NTOK) {
        float s = __hip_atomic_load(&Pacc[(size_t)b * NTOK + tid],
                                    __ATOMIC_RELAXED, __HIP_MEMORY_SCOPE_AGENT);
        v_log[tid] = -LOG2_N - __builtin_amdgcn_logf(s);
    }
    __syncthreads();
    float acc = 0.f;
    for (int idx = tid; idx < ROWS * NTOK; idx += 1024) {
        int r = idx / NTOK, m = idx - r * NTOK;
        float e = __half2float(Ms[r * MPITCH + m]);
        if (e > 0.f) {
            float msp = __builtin_amdgcn_logf(e) + mrow[r];
            acc = fmaf(__builtin_amdgcn_exp2f(u_l[r] + v_log[m]) * e, msp, acc);
        }
    }
#pragma unroll
    for (int off = 32; off > 0; off >>= 1) acc += __shfl_xor(acc, off, 64);
    if (lane == 0) red[wv] = acc;
    __syncthreads();
    if (tid == 0) {
        float s = 0.f;
#pragma unroll
        for (int w = 0; w < 16; w++) s += red[w];
        float old = __hip_atomic_fetch_add(gsum, s * M_FROM_MSP,
                                           __ATOMIC_RELAXED, __HIP_MEMORY_SCOPE_AGENT);
        int* dptr = done + ((old == -1.2345678e33f) ? 1 : 0);
        int prev = __hip_atomic_fetch_add(dptr, 1, __ATOMIC_RELAXED, __HIP_MEMORY_SCOPE_AGENT);
        if (prev == NWG - 1) {
            float tot = __hip_atomic_load(gsum, __ATOMIC_RELAXED, __HIP_MEMORY_SCOPE_AGENT);
            out[0] = tot * (1.0f / BSZ);
        }
    }
    if (dummy == -1.2345678e33f) dummyout[blockIdx.x] = 1.f;
}

extern "C" void kernel_launch(void* const* d_in, const int* in_sizes, int n_in,
                              void* d_out, int out_size, void* d_ws, size_t ws_size,
                              hipStream_t stream) {
    const float* feat_s = (const float*)d_in[0];
    const float* feat_t = (const float*)d_in[1];
    const float* Ws = (const float*)d_in[2];
    const float* bs = (const float*)d_in[3];
    const float* Wt = (const float*)d_in[4];
    const float* bt = (const float*)d_in[5];

    char* ws = (char*)d_ws;
    int* counters  = (int*)(ws + OFF_CNT);
    int* done      = (int*)(ws + OFF_DONE);
    float* gsum    = (float*)(ws + OFF_GSUM);
    float* dummyo  = (float*)(ws + OFF_DUMMY);
    float* sumsq   = (float*)(ws + OFF_SQS);
    float* Pacc    = (float*)(ws + OFF_PACC);
    __half* xs     = (__half*)(ws + OFF_XS);
    __half* xt     = (__half*)(ws + OFF_XT);
    float* out = (float*)d_out;

    hipMemsetAsync(ws, 0, MEMSET_BYTES, stream);

    hipLaunchKernelGGL(k1_proj, dim3(9, 32, 2), dim3(512), 0, stream,
                       feat_s, feat_t, Ws, bs, Wt, bt, xs, xt, sumsq);

    (void)hipFuncSetAttribute((const void*)k4_sinkhorn,
                              hipFuncAttributeMaxDynamicSharedMemorySize, SMEM_BYTES);
    hipLaunchKernelGGL(k4_sinkhorn, dim3(NWG), dim3(1024), SMEM_BYTES, stream,
                       xs, xt, sumsq, Pacc, counters, done, gsum, dummyo, out);
}